// Round 1
// baseline (442.703 us; speedup 1.0000x reference)
//
#include <hip/hip_runtime.h>

#define B_SZ 2048
#define OBS_DIM 4096
#define N_GVFS 4096
#define IPG 16
#define HPG 8
#define N_ACT 18
#define TOTAL_FEAT (OBS_DIM + HPG * N_GVFS) /* 36864 */

#define BT 8          /* batch rows per block */
#define NTHREADS 512
#define GPT (N_GVFS / NTHREADS) /* 8 gvfs per thread */

// ---------------------------------------------------------------------------
// Pre-kernel: transpose gvf_W [g][h][i] -> Wt [g][i][h] so stage-1 reads of
// "all h for one i" are contiguous (2 x float4).
// ---------------------------------------------------------------------------
__global__ void wt_transpose_kernel(const float* __restrict__ W,
                                    float* __restrict__ Wt) {
    const int g = blockIdx.x;
    const int e = threadIdx.x; // 0..127 ; e = h*16 + i
    const float v = W[g * 128 + e];
    const int h = e >> 4;
    const int i = e & 15;
    Wt[g * 128 + i * 8 + h] = v;
}

// ---------------------------------------------------------------------------
// Fused kernel: one block = 8 batch rows.
//  Phase A: stage obs tile in LDS, column-major (column j = 8 rows = 32 B),
//           parity-swizzled: rows0-3 half at byte j*32 + (j&1)*16,
//           rows4-7 half at the other 16 B.  -> random ds_read_b128 gathers
//           land uniformly on all 8 16-B slots per 128-B bank row.
//  Phase B: per thread: 8 gvfs; gather inputs as b128 column reads, 16->8
//           relu MLP, fold directly into qacc[8][18] with q_W gvf columns.
//  Phase C: fold the obs part of the Q head into the same qacc.
//  Phase D: 4-chunk LDS reduction (reuses obs LDS) -> 144 outputs per block.
// ---------------------------------------------------------------------------
template <int WT_MODE>
__global__ __launch_bounds__(NTHREADS, 2)
void fused_gvf_q_kernel(const float* __restrict__ obs,
                        const float* __restrict__ Wt,   // [g][i][h] if WT_MODE else [g][h][i]
                        const float* __restrict__ qW,   // [a][36864]
                        const int*   __restrict__ gidx, // [g][16]
                        float* __restrict__ out)        // [b][18]
{
    __shared__ __align__(16) float smem[OBS_DIM * BT]; // 128 KiB
    __shared__ float red2[36][16];

    const int tid = threadIdx.x;
    const int b0  = blockIdx.x * BT;
    char* const smem_b = (char*)smem;

    // ---------------- Phase A: obs tile -> LDS (column-major, swizzled) ----
    for (int m = 0; m < 16; ++m) {
        const int id  = tid + NTHREADS * m;   // float4 id over the tile
        const int row = id & 7;
        const int j4  = id >> 3;              // 0..1023
        const float4 v4 = *(const float4*)(obs + (size_t)(b0 + row) * OBS_DIM + j4 * 4);
        const float vv[4] = {v4.x, v4.y, v4.z, v4.w};
#pragma unroll
        for (int c = 0; c < 4; ++c) {
            const int j = j4 * 4 + c;
            const int byteoff = (j << 5) + ((((row >> 2) ^ (j & 1)) & 1) << 4) + ((row & 3) << 2);
            *(float*)(smem_b + byteoff) = vv[c];
        }
    }
    __syncthreads();

    float qacc[BT][N_ACT];
#pragma unroll
    for (int r = 0; r < BT; ++r)
#pragma unroll
        for (int a = 0; a < N_ACT; ++a) qacc[r][a] = 0.f;

    // ---------------- Phase B: GVF MLP + Q-head gvf part -------------------
#pragma unroll 1
    for (int k = 0; k < GPT; ++k) {
        const int g = tid + NTHREADS * k;
        const float* wg = Wt + (size_t)g * (IPG * HPG);
        const float* qg = qW + OBS_DIM + (size_t)g * HPG;
        const int*   gi = gidx + g * IPG;

        float v[8][8];
#pragma unroll
        for (int r = 0; r < 8; ++r)
#pragma unroll
            for (int h = 0; h < 8; ++h) v[r][h] = 0.f;

#pragma unroll
        for (int i = 0; i < IPG; ++i) {
            const int j  = gi[i];
            const int cb = (j << 5) | ((j & 1) << 4); // half holding rows 0-3
            const float4 xa = *(const float4*)(smem_b + cb);
            const float4 xb = *(const float4*)(smem_b + (cb ^ 16));
            const float xr[8] = {xa.x, xa.y, xa.z, xa.w, xb.x, xb.y, xb.z, xb.w};
            float w[8];
            if constexpr (WT_MODE) {
                const float4 w0 = *(const float4*)(wg + i * 8);
                const float4 w1 = *(const float4*)(wg + i * 8 + 4);
                w[0]=w0.x; w[1]=w0.y; w[2]=w0.z; w[3]=w0.w;
                w[4]=w1.x; w[5]=w1.y; w[6]=w1.z; w[7]=w1.w;
            } else {
#pragma unroll
                for (int h = 0; h < 8; ++h) w[h] = wg[h * IPG + i];
            }
#pragma unroll
            for (int r = 0; r < 8; ++r)
#pragma unroll
                for (int h = 0; h < 8; ++h)
                    v[r][h] = fmaf(xr[r], w[h], v[r][h]);
        }
        // relu
#pragma unroll
        for (int r = 0; r < 8; ++r)
#pragma unroll
            for (int h = 0; h < 8; ++h) v[r][h] = fmaxf(v[r][h], 0.f);

        // q head, gvf columns: qacc[r][a] += sum_h v[r][h] * qW[a][4096+g*8+h]
#pragma unroll
        for (int a = 0; a < N_ACT; ++a) {
            const float4 q0 = *(const float4*)(qg + (size_t)a * TOTAL_FEAT);
            const float4 q1 = *(const float4*)(qg + (size_t)a * TOTAL_FEAT + 4);
            const float qh[8] = {q0.x, q0.y, q0.z, q0.w, q1.x, q1.y, q1.z, q1.w};
#pragma unroll
            for (int r = 0; r < 8; ++r) {
                float acc = qacc[r][a];
#pragma unroll
                for (int h = 0; h < 8; ++h) acc = fmaf(v[r][h], qh[h], acc);
                qacc[r][a] = acc;
            }
        }
    }

    // ---------------- Phase C: Q-head obs part -----------------------------
#pragma unroll 1
    for (int jj = 0; jj < OBS_DIM / NTHREADS; ++jj) {
        const int j  = jj * NTHREADS + tid;
        const int cb = (j << 5) | ((j & 1) << 4);
        const float4 xa = *(const float4*)(smem_b + cb);
        const float4 xb = *(const float4*)(smem_b + (cb ^ 16));
        const float xr[8] = {xa.x, xa.y, xa.z, xa.w, xb.x, xb.y, xb.z, xb.w};
#pragma unroll
        for (int a = 0; a < N_ACT; ++a) {
            const float qc = qW[(size_t)a * TOTAL_FEAT + j];
#pragma unroll
            for (int r = 0; r < 8; ++r)
                qacc[r][a] = fmaf(qc, xr[r], qacc[r][a]);
        }
    }

    // ---------------- Phase D: reduce 512 partials -> 144 outputs ----------
    // 4 chunks of 36 accumulators; red[k][512] aliases the obs LDS.
    float* red = smem;
    const int kk = tid / 14;  // 0..35 for tid<504
    const int jl = tid % 14;
#pragma unroll 1
    for (int c = 0; c < 4; ++c) {
        __syncthreads(); // retire previous consumers of smem/red2
#pragma unroll
        for (int k2 = 0; k2 < 36; ++k2) {
            const int flat = c * 36 + k2;           // compile-time after unroll
            red[k2 * NTHREADS + tid] = qacc[flat / N_ACT][flat % N_ACT];
        }
        __syncthreads();
        if (tid < 504) {
            float s = 0.f;
            for (int sc = jl; sc < NTHREADS; sc += 14) s += red[kk * NTHREADS + sc];
            red2[kk][jl] = s;
        }
        __syncthreads();
        if (tid < 36) {
            float s = 0.f;
#pragma unroll
            for (int q = 0; q < 14; ++q) s += red2[tid][q];
            out[(size_t)b0 * N_ACT + c * 36 + tid] = s;
        }
    }
}

// ---------------------------------------------------------------------------
extern "C" void kernel_launch(void* const* d_in, const int* in_sizes, int n_in,
                              void* d_out, int out_size, void* d_ws, size_t ws_size,
                              hipStream_t stream) {
    const float* obs  = (const float*)d_in[0];
    const float* gvfW = (const float*)d_in[1];
    const float* qW   = (const float*)d_in[2];
    const int*   gidx = (const int*)d_in[3];
    float* out = (float*)d_out;

    const size_t wt_bytes = (size_t)N_GVFS * IPG * HPG * sizeof(float); // 2 MiB
    const dim3 grid(B_SZ / BT), blk(NTHREADS);

    if (ws_size >= wt_bytes) {
        float* wt = (float*)d_ws;
        wt_transpose_kernel<<<dim3(N_GVFS), dim3(128), 0, stream>>>(gvfW, wt);
        fused_gvf_q_kernel<1><<<grid, blk, 0, stream>>>(obs, wt, qW, gidx, out);
    } else {
        fused_gvf_q_kernel<0><<<grid, blk, 0, stream>>>(obs, gvfW, qW, gidx, out);
    }
}

// Round 2
// 327.259 us; speedup vs baseline: 1.3528x; 1.3528x over previous
//
#include <hip/hip_runtime.h>

#define B_SZ 2048
#define OBS_DIM 4096
#define N_GVFS 4096
#define IPG 16
#define HPG 8
#define N_ACT 18
#define TOTAL_FEAT (OBS_DIM + HPG * N_GVFS) /* 36864 */

#define BT 8                 /* batch rows per block */
#define NTHREADS 512
#define RPT 4                /* rows per thread */
#define TPG 256              /* threads per row-group */
#define GPT (N_GVFS / TPG)   /* 16 gvfs per thread */

// ---------------------------------------------------------------------------
// Pre-kernel: transpose gvf_W [g][h][i] -> Wt [g][i][h] so stage-1 reads of
// "all h for one i" are contiguous (2 x float4).
// ---------------------------------------------------------------------------
__global__ void wt_transpose_kernel(const float* __restrict__ W,
                                    float* __restrict__ Wt) {
    const int g = blockIdx.x;
    const int e = threadIdx.x; // 0..127 ; e = h*16 + i
    const float v = W[g * 128 + e];
    const int h = e >> 4;
    const int i = e & 15;
    Wt[g * 128 + i * 8 + h] = v;
}

// ---------------------------------------------------------------------------
// Fused kernel: one block = 8 batch rows; two row-groups of 256 threads.
//  Phase A: obs tile -> LDS, column-major (column j = 8 rows = 32 B),
//           parity-swizzled halves so random b128 gathers spread over banks.
//  Phase B: per thread: 16 gvfs x 4 rows; gather inputs as one b128 column
//           read (its row-group's half), 16->8 relu MLP, fold into
//           qacc[4][18] with q_W gvf columns.
//  Phase C: fold the obs part of the Q head into qacc (group covers all j
//           for its 4 rows).
//  Phase D: wave shuffle-reduce (static indices!) -> red2 -> 144 outputs.
//  NOTE: every local-array index is compile-time constant (rule #20: runtime
//  indexing demotes arrays to scratch — that was round 1's 1.17 GB of HBM
//  writes and the entire 409 us).
// ---------------------------------------------------------------------------
template <int WT_MODE>
__global__ __launch_bounds__(NTHREADS, 2)
void fused_gvf_q_kernel(const float* __restrict__ obs,
                        const float* __restrict__ Wt,   // [g][i][h] if WT_MODE else [g][h][i]
                        const float* __restrict__ qW,   // [a][36864]
                        const int*   __restrict__ gidx, // [g][16]
                        float* __restrict__ out)        // [b][18]
{
    __shared__ __align__(16) float smem[OBS_DIM * BT]; // 128 KiB
    __shared__ float red2[8][RPT][N_ACT];              // per-wave partials

    const int tid = threadIdx.x;
    const int b0  = blockIdx.x * BT;
    char* const smem_b = (char*)smem;

    // ---------------- Phase A: obs tile -> LDS (column-major, swizzled) ----
    for (int m = 0; m < 16; ++m) {
        const int id  = tid + NTHREADS * m;   // float4 id over the tile
        const int row = id & 7;
        const int j4  = id >> 3;              // 0..1023
        const float4 v4 = *(const float4*)(obs + (size_t)(b0 + row) * OBS_DIM + j4 * 4);
        const float vv[4] = {v4.x, v4.y, v4.z, v4.w};
#pragma unroll
        for (int c = 0; c < 4; ++c) {
            const int j = j4 * 4 + c;
            const int byteoff = (j << 5) + ((((row >> 2) ^ (j & 1)) & 1) << 4) + ((row & 3) << 2);
            *(float*)(smem_b + byteoff) = vv[c];
        }
    }
    __syncthreads();

    const int h  = tid >> 8;   // row-group: rows h*4 .. h*4+3
    const int tg = tid & 255;  // index within group

    float qacc[RPT][N_ACT];
#pragma unroll
    for (int r = 0; r < RPT; ++r)
#pragma unroll
        for (int a = 0; a < N_ACT; ++a) qacc[r][a] = 0.f;

    // ---------------- Phase B: GVF MLP + Q-head gvf part -------------------
#pragma unroll 1
    for (int k = 0; k < GPT; ++k) {
        const int g = tg + TPG * k;
        const float* wg = Wt + (size_t)g * (IPG * HPG);
        const float* qg = qW + OBS_DIM + (size_t)g * HPG;

        int jv[IPG];
        {
            const int4* gi4 = (const int4*)(gidx + g * IPG);
#pragma unroll
            for (int q = 0; q < 4; ++q) {
                const int4 t4 = gi4[q];
                jv[q * 4 + 0] = t4.x; jv[q * 4 + 1] = t4.y;
                jv[q * 4 + 2] = t4.z; jv[q * 4 + 3] = t4.w;
            }
        }

        float v[RPT][HPG];
#pragma unroll
        for (int r = 0; r < RPT; ++r)
#pragma unroll
            for (int hh = 0; hh < HPG; ++hh) v[r][hh] = 0.f;

#pragma unroll
        for (int i = 0; i < IPG; ++i) {
            const int j   = jv[i];
            const int off = (j << 5) + (((h ^ (j & 1)) & 1) << 4); // this group's half
            const float4 x4 = *(const float4*)(smem_b + off);
            const float xr[RPT] = {x4.x, x4.y, x4.z, x4.w};
            float w[HPG];
            if constexpr (WT_MODE) {
                const float4 w0 = *(const float4*)(wg + i * 8);
                const float4 w1 = *(const float4*)(wg + i * 8 + 4);
                w[0]=w0.x; w[1]=w0.y; w[2]=w0.z; w[3]=w0.w;
                w[4]=w1.x; w[5]=w1.y; w[6]=w1.z; w[7]=w1.w;
            } else {
#pragma unroll
                for (int hh = 0; hh < HPG; ++hh) w[hh] = wg[hh * IPG + i];
            }
#pragma unroll
            for (int r = 0; r < RPT; ++r)
#pragma unroll
                for (int hh = 0; hh < HPG; ++hh)
                    v[r][hh] = fmaf(xr[r], w[hh], v[r][hh]);
        }
        // relu
#pragma unroll
        for (int r = 0; r < RPT; ++r)
#pragma unroll
            for (int hh = 0; hh < HPG; ++hh) v[r][hh] = fmaxf(v[r][hh], 0.f);

        // q head, gvf columns: qacc[r][a] += sum_h v[r][h] * qW[a][4096+g*8+h]
#pragma unroll
        for (int a = 0; a < N_ACT; ++a) {
            const float4 q0 = *(const float4*)(qg + (size_t)a * TOTAL_FEAT);
            const float4 q1 = *(const float4*)(qg + (size_t)a * TOTAL_FEAT + 4);
            const float qh[HPG] = {q0.x, q0.y, q0.z, q0.w, q1.x, q1.y, q1.z, q1.w};
            float acc0 = qacc[0][a], acc1 = qacc[1][a], acc2 = qacc[2][a], acc3 = qacc[3][a];
#pragma unroll
            for (int hh = 0; hh < HPG; ++hh) {
                acc0 = fmaf(v[0][hh], qh[hh], acc0);
                acc1 = fmaf(v[1][hh], qh[hh], acc1);
                acc2 = fmaf(v[2][hh], qh[hh], acc2);
                acc3 = fmaf(v[3][hh], qh[hh], acc3);
            }
            qacc[0][a] = acc0; qacc[1][a] = acc1; qacc[2][a] = acc2; qacc[3][a] = acc3;
        }
    }

    // ---------------- Phase C: Q-head obs part -----------------------------
#pragma unroll 1
    for (int jj = 0; jj < OBS_DIM / TPG; ++jj) { // 16
        const int j   = tg + TPG * jj;
        const int off = (j << 5) + (((h ^ (j & 1)) & 1) << 4);
        const float4 x4 = *(const float4*)(smem_b + off);
        const float xr[RPT] = {x4.x, x4.y, x4.z, x4.w};
#pragma unroll
        for (int a = 0; a < N_ACT; ++a) {
            const float qc = qW[(size_t)a * TOTAL_FEAT + j];
#pragma unroll
            for (int r = 0; r < RPT; ++r)
                qacc[r][a] = fmaf(qc, xr[r], qacc[r][a]);
        }
    }

    // ---------------- Phase D: wave shuffle reduce -> 144 outputs ----------
    // Waves 0-3 are row-group 0 (rows 0-3), waves 4-7 group 1 (rows 4-7).
    const int wv = tid >> 6;
#pragma unroll
    for (int r = 0; r < RPT; ++r)
#pragma unroll
        for (int a = 0; a < N_ACT; ++a) {
            float s = qacc[r][a];
#pragma unroll
            for (int m = 1; m < 64; m <<= 1)
                s += __shfl_xor(s, m, 64);
            if ((tid & 63) == 0) red2[wv][r][a] = s;
        }
    __syncthreads();
    if (tid < BT * N_ACT) { // 144
        const int row = tid / N_ACT;
        const int a   = tid % N_ACT;
        const int hg  = row >> 2;
        const int r   = row & 3;
        float s = 0.f;
#pragma unroll
        for (int w2 = 0; w2 < 4; ++w2) s += red2[hg * 4 + w2][r][a];
        out[(size_t)(b0 + row) * N_ACT + a] = s;
    }
}

// ---------------------------------------------------------------------------
extern "C" void kernel_launch(void* const* d_in, const int* in_sizes, int n_in,
                              void* d_out, int out_size, void* d_ws, size_t ws_size,
                              hipStream_t stream) {
    const float* obs  = (const float*)d_in[0];
    const float* gvfW = (const float*)d_in[1];
    const float* qW   = (const float*)d_in[2];
    const int*   gidx = (const int*)d_in[3];
    float* out = (float*)d_out;

    const size_t wt_bytes = (size_t)N_GVFS * IPG * HPG * sizeof(float); // 2 MiB
    const dim3 grid(B_SZ / BT), blk(NTHREADS);

    if (ws_size >= wt_bytes) {
        float* wt = (float*)d_ws;
        wt_transpose_kernel<<<dim3(N_GVFS), dim3(128), 0, stream>>>(gvfW, wt);
        fused_gvf_q_kernel<1><<<grid, blk, 0, stream>>>(obs, wt, qW, gidx, out);
    } else {
        fused_gvf_q_kernel<0><<<grid, blk, 0, stream>>>(obs, gvfW, qW, gidx, out);
    }
}